// Round 5
// baseline (106.918 us; speedup 1.0000x reference)
//
#include <hip/hip_runtime.h>
#include <cfloat>

// ChamferLossKL: bs=8, n=2048, d=4, fp32, one-pass over the pair matrix.
// s_ij = 2*KL(pred_i||gt_j) = dot(pa_i,ivb_j) + dot(mua_i,m2_j) + ca_i + cb_j
//   row (pred) record: pa = exp(lva)+mua^2 (4), mua (4), ca = -sum(lva)-4
//   col (gt)   record: ivb = exp(-lvb) (4), m2 = -2*mub*ivb (4),
//                      cb = sum(mub^2*ivb)+sum(lvb)
// Seeding the FMA chain with ca and adding cb at the end gives s = 2*KL
// directly; row-min and col-min are mins of the SAME s, so
// loss[b] = 0.5*( sum_i min_j s + sum_j min_i s ).
//
// R4->R5: R4 spilled (VGPR_Count=60 vs ~105 live -> 97us, VALUBusy 12%).
// Fix: TPB=512 + __launch_bounds__(512,4) (VGPR cap 128), RPT=8 (~100 live),
// 2 blocks/CU. Pair math down to 11 ops via the ca-seeded chain.

#define TPB     512
#define WAVES   8
#define RPT     8
#define ROWSPB  (WAVES * RPT)     // 64 rows per block
#define NFIX    2048
#define CH_COLS 1024              // columns per block (z-dim halves)
#define NRG     (NFIX / ROWSPB)   // 32 row groups
#define BPB     (NRG * 2)         // 64 blocks per batch

__device__ __forceinline__ unsigned enc_f32(float f) {
    unsigned u = __float_as_uint(f);
    return (u & 0x80000000u) ? ~u : (u | 0x80000000u);
}
__device__ __forceinline__ float dec_f32(unsigned e) {
    return (e & 0x80000000u) ? __uint_as_float(e ^ 0x80000000u)
                             : __uint_as_float(~e);
}

__global__ __launch_bounds__(TPB, 4) void chamfer_kl_onepass(
    const float4* __restrict__ mu_a, const float4* __restrict__ lv_a,
    const float4* __restrict__ mu_b, const float4* __restrict__ lv_b,
    float* __restrict__ rowpart,     // [8][2][2048]
    float* __restrict__ colpart,     // [8][32][2048]
    unsigned* __restrict__ counters, // [8]
    float* __restrict__ out)
{
    __shared__ float4   sv0[CH_COLS];   // ivb   16 KB
    __shared__ float4   sv1[CH_COLS];   // m2    16 KB
    __shared__ float    scb[CH_COLS];   // cb     4 KB
    __shared__ unsigned scm[CH_COLS];   // enc min 4 KB
    __shared__ float    fsum[WAVES];
    __shared__ unsigned sOld;

    const int t    = threadIdx.x;
    const int rg   = blockIdx.x;     // 32 row groups
    const int b    = blockIdx.y;     // 8 batches
    const int ch   = blockIdx.z;     // 2 column halves
    const int lane = t & 63;
    const int wid  = t >> 6;
    const int n    = NFIX;

    // ---- stage this half's column records (gts -> B-type), 2 per thread
    for (int i = t; i < CH_COLS; i += TPB) {
        const int j = ch * CH_COLS + i;
        float4 mu = mu_b[(size_t)b * n + j];
        float4 lv = lv_b[(size_t)b * n + j];
        float4 iv = make_float4(__expf(-lv.x), __expf(-lv.y),
                                __expf(-lv.z), __expf(-lv.w));
        sv0[i] = iv;
        sv1[i] = make_float4(-2.f * mu.x * iv.x, -2.f * mu.y * iv.y,
                             -2.f * mu.z * iv.z, -2.f * mu.w * iv.w);
        scb[i] = mu.x * mu.x * iv.x + mu.y * mu.y * iv.y
               + mu.z * mu.z * iv.z + mu.w * mu.w * iv.w
               + lv.x + lv.y + lv.z + lv.w;
        scm[i] = 0xFFFFFFFFu;
    }

    // ---- row records (preds -> A-type), 8 rows per thread
    const int rbase = rg * ROWSPB + wid * RPT;
    float4 r0[RPT], r1[RPT];
    float  rc[RPT], rmin[RPT];
#pragma unroll
    for (int r = 0; r < RPT; ++r) {
        float4 mu = mu_a[(size_t)b * n + rbase + r];
        float4 lv = lv_a[(size_t)b * n + rbase + r];
        r0[r] = make_float4(__expf(lv.x) + mu.x * mu.x,
                            __expf(lv.y) + mu.y * mu.y,
                            __expf(lv.z) + mu.z * mu.z,
                            __expf(lv.w) + mu.w * mu.w);
        r1[r] = mu;
        rc[r] = -(lv.x + lv.y + lv.z + lv.w) - 4.f;
        rmin[r] = FLT_MAX;
    }
    __syncthreads();

    // ---- main sweep: 64 rows x 1024 cols, each pair once, s = 2*KL
    for (int jj = 0; jj < CH_COLS / 64; ++jj) {
        const int j = (jj << 6) + lane;
        const float4 c0 = sv0[j];
        const float4 c1 = sv1[j];
        const float  cb = scb[j];
        float cmin = FLT_MAX;
#pragma unroll
        for (int r = 0; r < RPT; ++r) {
            float s = fmaf(r0[r].x, c0.x, rc[r]);   // seeded with ca_i
            s = fmaf(r0[r].y, c0.y, s);
            s = fmaf(r0[r].z, c0.z, s);
            s = fmaf(r0[r].w, c0.w, s);
            s = fmaf(r1[r].x, c1.x, s);
            s = fmaf(r1[r].y, c1.y, s);
            s = fmaf(r1[r].z, c1.z, s);
            s = fmaf(r1[r].w, c1.w, s);
            s += cb;                                 // s = 2*KL(i,j)
            rmin[r] = fminf(rmin[r], s);
            cmin    = fminf(cmin, s);
        }
        atomicMin(&scm[j], enc_f32(cmin));           // ds_min_u32, no conflict
    }
    __syncthreads();

    // ---- col partials for this row group (coalesced stores)
    for (int i = t; i < CH_COLS; i += TPB)
        colpart[((size_t)b * NRG + rg) * n + ch * CH_COLS + i] = dec_f32(scm[i]);

    // ---- row partials: min across 64 lanes per row
    {
        float* rp = rowpart + ((size_t)b * 2 + ch) * n + rbase;
#pragma unroll
        for (int r = 0; r < RPT; ++r) {
            float m = rmin[r];
#pragma unroll
            for (int off = 32; off; off >>= 1)
                m = fminf(m, __shfl_xor(m, off, 64));
            if (lane == 0) rp[r] = m;
        }
    }

    // ---- last of the 64 blocks of this batch finalizes it.
    // mod-64 trick works for ANY initial counter value (0xAA poison ok).
    __threadfence();
    if (t == 0)
        sOld = __hip_atomic_fetch_add(&counters[b], 1u,
                                      __ATOMIC_ACQ_REL, __HIP_MEMORY_SCOPE_AGENT);
    __syncthreads();
    if ((sOld & 63u) != 63u) return;
    __threadfence();

    float acc = 0.f;
    for (int j = t; j < n; j += TPB) {      // 4 iterations
        float m = FLT_MAX;
#pragma unroll
        for (int g = 0; g < NRG; ++g)
            m = fminf(m, colpart[((size_t)b * NRG + g) * n + j]);
        acc += m;
    }
    for (int i = t; i < n; i += TPB)        // 4 iterations
        acc += fminf(rowpart[((size_t)b * 2 + 0) * n + i],
                     rowpart[((size_t)b * 2 + 1) * n + i]);
#pragma unroll
    for (int off = 32; off; off >>= 1) acc += __shfl_xor(acc, off, 64);
    if (lane == 0) fsum[wid] = acc;
    __syncthreads();
    if (wid == 0) {
        float v = (lane < WAVES) ? fsum[lane] : 0.f;
#pragma unroll
        for (int off = 4; off; off >>= 1) v += __shfl_xor(v, off, 64);
        if (t == 0) out[b] = 0.5f * v;
    }
}

extern "C" void kernel_launch(void* const* d_in, const int* in_sizes, int n_in,
                              void* d_out, int out_size, void* d_ws, size_t ws_size,
                              hipStream_t stream) {
    const float4* mu_a = (const float4*)d_in[0];  // mu_preds
    const float4* lv_a = (const float4*)d_in[1];  // logvar_preds
    const float4* mu_b = (const float4*)d_in[2];  // mu_gts
    const float4* lv_b = (const float4*)d_in[3];  // logvar_gts

    const int bs = out_size;  // 8

    float* ws = (float*)d_ws;
    float*    colpart  = ws;                                           // 8*32*2048
    float*    rowpart  = ws + (size_t)bs * NRG * NFIX;                 // 8*2*2048
    unsigned* counters = (unsigned*)(rowpart + (size_t)bs * 2 * NFIX); // 8

    dim3 grid(NRG, bs, 2);  // (32, 8, 2) = 512 blocks, 2/CU
    chamfer_kl_onepass<<<grid, TPB, 0, stream>>>(mu_a, lv_a, mu_b, lv_b,
                                                 rowpart, colpart, counters,
                                                 (float*)d_out);
}

// Round 7
// 21.805 us; speedup vs baseline: 4.9033x; 4.9033x over previous
//
#include <hip/hip_runtime.h>
#include <cfloat>

// ChamferLossKL: bs=8, n=2048, d=4, fp32, one-pass over the pair matrix.
// s_ij = 2*KL(pred_i||gt_j) = dot(pa_i,ivb_j) + dot(mua_i,m2_j) + ca_i + cb_j
//   row (pred) record: pa = exp(lva)+mua^2 (4), mua (4), ca = -sum(lva)-4
//   col (gt)   record: ivb = exp(-lvb) (4), m2 = -2*mub*ivb (4),
//                      cb = sum(mub^2*ivb)+sum(lvb)
// Chain seeded with ca, cb added last -> s = 2*KL; row-min (regs+shuffle)
// and col-min (LDS ds_min_u32, monotone encoding) of the SAME s.
// loss[b] = 0.5*(sum_i min_j s + sum_j min_i s).
//
// R6->R7: R4-R6's "mod-64 counter" finalize was WRONG BY DESIGN: with the
// counter starting at poison (0xAA.. = 42 mod 64), the block seeing
// old&63==63 is the 22nd incrementer, not the last -> finalize raced 42
// unfinished blocks (R6 absmax 1280 ~ half the sum missing; R4/R5 passed on
// luck). Fix: two kernels, the boundary is the barrier. Spill fix kept:
// __launch_bounds__(1024,4) -> VGPR cap 128 (R4/R5 allocator targeted
// 64-cap/8-wave and spilled ~95 live regs -> VALUBusy 11%, 100us).

#define TPB     1024
#define WAVES   16
#define RPT     8
#define ROWSPB  (WAVES * RPT)     // 128 rows per block
#define NFIX    2048
#define CH_COLS 1024              // columns per block (z-dim halves)
#define NRG     (NFIX / ROWSPB)   // 16 row groups

__device__ __forceinline__ unsigned enc_f32(float f) {
    unsigned u = __float_as_uint(f);
    return (u & 0x80000000u) ? ~u : (u | 0x80000000u);
}
__device__ __forceinline__ float dec_f32(unsigned e) {
    return (e & 0x80000000u) ? __uint_as_float(e ^ 0x80000000u)
                             : __uint_as_float(~e);
}

__global__ __launch_bounds__(TPB, 4) void chamfer_kl_main(
    const float4* __restrict__ mu_a, const float4* __restrict__ lv_a,
    const float4* __restrict__ mu_b, const float4* __restrict__ lv_b,
    float* __restrict__ rowpart,     // [8][2][2048]
    float* __restrict__ colpart)     // [8][16][2048]
{
    __shared__ float4   sv0[CH_COLS];   // ivb     16 KB
    __shared__ float4   sv1[CH_COLS];   // m2      16 KB
    __shared__ float    scb[CH_COLS];   // cb       4 KB
    __shared__ unsigned scm[CH_COLS];   // enc min  4 KB

    const int t    = threadIdx.x;
    const int rg   = blockIdx.x;     // 16 row groups
    const int b    = blockIdx.y;     // 8 batches
    const int ch   = blockIdx.z;     // 2 column halves
    const int lane = t & 63;
    const int wid  = t >> 6;
    const int n    = NFIX;

    // ---- stage this half's column records (gts -> B-type), 1 per thread
    {
        const int j = ch * CH_COLS + t;
        float4 mu = mu_b[(size_t)b * n + j];
        float4 lv = lv_b[(size_t)b * n + j];
        float4 iv = make_float4(__expf(-lv.x), __expf(-lv.y),
                                __expf(-lv.z), __expf(-lv.w));
        sv0[t] = iv;
        sv1[t] = make_float4(-2.f * mu.x * iv.x, -2.f * mu.y * iv.y,
                             -2.f * mu.z * iv.z, -2.f * mu.w * iv.w);
        scb[t] = mu.x * mu.x * iv.x + mu.y * mu.y * iv.y
               + mu.z * mu.z * iv.z + mu.w * mu.w * iv.w
               + lv.x + lv.y + lv.z + lv.w;
        scm[t] = 0xFFFFFFFFu;
    }

    // ---- row records (preds -> A-type), 8 rows per thread (wave-uniform)
    const int rbase = rg * ROWSPB + wid * RPT;
    float4 r0[RPT], r1[RPT];
    float  rc[RPT], rmin[RPT];
#pragma unroll
    for (int r = 0; r < RPT; ++r) {
        float4 mu = mu_a[(size_t)b * n + rbase + r];
        float4 lv = lv_a[(size_t)b * n + rbase + r];
        r0[r] = make_float4(__expf(lv.x) + mu.x * mu.x,
                            __expf(lv.y) + mu.y * mu.y,
                            __expf(lv.z) + mu.z * mu.z,
                            __expf(lv.w) + mu.w * mu.w);
        r1[r] = mu;
        rc[r] = -(lv.x + lv.y + lv.z + lv.w) - 4.f;
        rmin[r] = FLT_MAX;
    }
    __syncthreads();

    // ---- main sweep: 128 rows x 1024 cols, each pair once, s = 2*KL
    for (int jj = 0; jj < CH_COLS / 64; ++jj) {
        const int j = (jj << 6) + lane;
        const float4 c0 = sv0[j];
        const float4 c1 = sv1[j];
        const float  cb = scb[j];
        float cmin = FLT_MAX;
#pragma unroll
        for (int r = 0; r < RPT; ++r) {
            float s = fmaf(r0[r].x, c0.x, rc[r]);   // seeded with ca_i
            s = fmaf(r0[r].y, c0.y, s);
            s = fmaf(r0[r].z, c0.z, s);
            s = fmaf(r0[r].w, c0.w, s);
            s = fmaf(r1[r].x, c1.x, s);
            s = fmaf(r1[r].y, c1.y, s);
            s = fmaf(r1[r].z, c1.z, s);
            s = fmaf(r1[r].w, c1.w, s);
            s += cb;                                 // s = 2*KL(i,j)
            rmin[r] = fminf(rmin[r], s);
            cmin    = fminf(cmin, s);
        }
        atomicMin(&scm[j], enc_f32(cmin));           // ds_min_u32
    }
    __syncthreads();

    // ---- col partials for this row group (coalesced stores)
    colpart[((size_t)b * NRG + rg) * n + ch * CH_COLS + t] = dec_f32(scm[t]);

    // ---- row partials: min across 64 lanes per row
    float* rp = rowpart + ((size_t)b * 2 + ch) * n + rbase;
#pragma unroll
    for (int r = 0; r < RPT; ++r) {
        float m = rmin[r];
#pragma unroll
        for (int off = 32; off; off >>= 1)
            m = fminf(m, __shfl_xor(m, off, 64));
        if (lane == 0) rp[r] = m;
    }
}

// One block per batch: sum of col-mins (min over 16 row groups) plus sum of
// row-mins (min over 2 column halves). Kernel boundary guarantees all
// partials are visible; output is overwritten (poison-safe, deterministic).
__global__ __launch_bounds__(TPB) void chamfer_kl_reduce(
    const float* __restrict__ rowpart,   // [8][2][2048]
    const float* __restrict__ colpart,   // [8][16][2048]
    float* __restrict__ out)
{
    __shared__ float fsum[WAVES];
    const int t    = threadIdx.x;
    const int b    = blockIdx.x;
    const int lane = t & 63;
    const int wid  = t >> 6;
    const int n    = NFIX;

    float acc = 0.f;
#pragma unroll
    for (int it = 0; it < 2; ++it) {     // n / TPB
        const int j = it * TPB + t;
        float m = FLT_MAX;
#pragma unroll
        for (int g = 0; g < NRG; ++g)
            m = fminf(m, colpart[((size_t)b * NRG + g) * n + j]);
        acc += m;
        acc += fminf(rowpart[((size_t)b * 2 + 0) * n + j],
                     rowpart[((size_t)b * 2 + 1) * n + j]);
    }
#pragma unroll
    for (int off = 32; off; off >>= 1) acc += __shfl_xor(acc, off, 64);
    if (lane == 0) fsum[wid] = acc;
    __syncthreads();
    if (wid == 0) {
        float v = (lane < WAVES) ? fsum[lane] : 0.f;
#pragma unroll
        for (int off = 8; off; off >>= 1) v += __shfl_xor(v, off, 64);
        if (t == 0) out[b] = 0.5f * v;
    }
}

extern "C" void kernel_launch(void* const* d_in, const int* in_sizes, int n_in,
                              void* d_out, int out_size, void* d_ws, size_t ws_size,
                              hipStream_t stream) {
    const float4* mu_a = (const float4*)d_in[0];  // mu_preds
    const float4* lv_a = (const float4*)d_in[1];  // logvar_preds
    const float4* mu_b = (const float4*)d_in[2];  // mu_gts
    const float4* lv_b = (const float4*)d_in[3];  // logvar_gts

    const int bs = out_size;  // 8

    float* ws = (float*)d_ws;
    float* colpart = ws;                              // 8*16*2048 floats (1 MB)
    float* rowpart = ws + (size_t)bs * NRG * NFIX;    // 8*2*2048 floats

    dim3 grid(NRG, bs, 2);  // (16, 8, 2) = 256 blocks, 1/CU
    chamfer_kl_main<<<grid, TPB, 0, stream>>>(mu_a, lv_a, mu_b, lv_b,
                                              rowpart, colpart);
    chamfer_kl_reduce<<<bs, TPB, 0, stream>>>(rowpart, colpart, (float*)d_out);
}